// Round 9
// baseline (1163.612 us; speedup 1.0000x reference)
//
#include <hip/hip_runtime.h>

typedef unsigned short u16;
typedef unsigned int u32;
typedef __attribute__((ext_vector_type(8))) short bf16x8;
typedef __attribute__((ext_vector_type(4))) float f32x4;
typedef __attribute__((ext_vector_type(2))) float f32x2;
typedef __attribute__((ext_vector_type(4))) u16 u16x4;

#define NN 32768
#define NE 524288
#define NG 16

__device__ __forceinline__ float bf2f(u16 v){ u32 u=((u32)v)<<16; float f; __builtin_memcpy(&f,&u,4); return f; }
__device__ __forceinline__ u16 f2bf(float f){ u32 u; __builtin_memcpy(&u,&f,4); return (u16)((u + 0x7fffu + ((u>>16)&1u))>>16); }
__device__ __forceinline__ void splitf(float v, u16& hi, u16& lo){
  u16 h = f2bf(v); hi = h; lo = f2bf(v - bf2f(h));
}
__device__ __forceinline__ f32x4 MFMA(bf16x8 a, bf16x8 b, f32x4 c){
  return __builtin_amdgcn_mfma_f32_16x16x32_bf16(a,b,c,0,0,0);
}
// fragment-major weight access: chunk c = kk*8 + tile, lane-coalesced 16B/lane
__device__ __forceinline__ bf16x8 WF(const u16* W, int c, int lane){
  return *(const bf16x8*)&W[((c<<6) + lane)*8];
}

// ---------------- sort stack ----------------
__global__ __launch_bounds__(256) void k_hist(const int* __restrict__ dst, int* __restrict__ cnt){
  int e = blockIdx.x*256 + threadIdx.x;
  if (e < NE) atomicAdd(&cnt[dst[e]], 1);
}

__global__ __launch_bounds__(1024) void k_scan(const int* __restrict__ cnt, int* __restrict__ off, int* __restrict__ cur){
  __shared__ int sums[1024];
  int t = threadIdx.x;
  int base = t*32; int s = 0;
  for (int i=0;i<32;i++) s += cnt[base+i];
  sums[t] = s; __syncthreads();
  for (int d=1; d<1024; d<<=1){
    int v = (t>=d)? sums[t-d] : 0; __syncthreads();
    sums[t] += v; __syncthreads();
  }
  int excl = (t==0)?0:sums[t-1];
  for (int i=0;i<32;i++){ int idx=base+i; off[idx]=excl; cur[idx]=excl; excl += cnt[idx]; }
  if (t==1023) off[NN] = excl;
}

__global__ __launch_bounds__(256) void k_scatter(const int* __restrict__ ei, int* __restrict__ cur,
                                                 int* __restrict__ srcs, int* __restrict__ eids){
  int e = blockIdx.x*256 + threadIdx.x;
  if (e < NE){
    int d = ei[NE + e];
    int p = atomicAdd(&cur[d], 1);
    srcs[p] = ei[e] | (d<<16);
    eids[p] = e;
  }
}

// gather ea rows into the exact fragment order k_edge consumes
__global__ __launch_bounds__(256) void k_presort(const float* __restrict__ ea, const int* __restrict__ eids,
                                                 float* __restrict__ easf){
  int t = threadIdx.x;
  int w = t>>6, lam = t&63;
  int p = blockIdx.x*64 + 16*w + (lam&15);
  int e = eids[p];
  f32x4 v0 = *(const f32x4*)(ea + (size_t)e*32 + (lam>>4)*8);
  f32x4 v1 = *(const f32x4*)(ea + (size_t)e*32 + (lam>>4)*8 + 4);
  float* d = easf + (size_t)blockIdx.x*2048 + t*8;
  *(f32x4*)d = v0; *(f32x4*)(d+4) = v1;
}

// ---------------- weight -> fragment-major hi/lo ----------------
struct TP { const float* s[12]; u16* dh[12]; u16* dl[12]; int K[12]; };
__global__ __launch_bounds__(256) void k_transpose(TP tp){
  int b = blockIdx.x;
  const float* s = tp.s[b]; u16* dh = tp.dh[b]; u16* dl = tp.dl[b]; int K = tp.K[b];
  int nslots = K*16;
  for (int i = threadIdx.x; i < nslots; i += 256){
    int c = i>>6, lam = i&63;
    int kk = c>>3, tc = c&7;
    int srow = 32*kk + 8*(lam>>4);
    int scol = 16*tc + (lam&15);
    #pragma unroll
    for (int j=0;j<8;j++){
      float v = s[(size_t)(srow+j)*128 + scol];
      u16 h, l; splitf(v, h, l);
      dh[(size_t)i*8 + j] = h; dl[(size_t)i*8 + j] = l;
    }
  }
}

// ---------------- h0 = relu(x @ Wn + bn) ----------------
__global__ __launch_bounds__(256) void k_h0(const float* __restrict__ x,
    const u16* __restrict__ WnTh, const u16* __restrict__ WnTl,
    const float* __restrict__ bn, float* __restrict__ h){
  __shared__ u16 xth[128*72], xtl[128*72];
  int rb = blockIdx.x*128, t = threadIdx.x, lane = t&63;
  { int r = t & 127, p = t >> 7;
    const f32x4* s = (const f32x4*)(x + (size_t)(rb+r)*64 + p*32);
    #pragma unroll
    for (int i=0;i<8;i++){
      f32x4 v = s[i];
      u16x4 oh, ol;
      #pragma unroll
      for (int j=0;j<4;j++){ u16 hh,ll; splitf(v[j],hh,ll); oh[j]=hh; ol[j]=ll; }
      *(u16x4*)&xth[r*72 + p*32 + 4*i] = oh;
      *(u16x4*)&xtl[r*72 + p*32 + 4*i] = ol;
    }
  }
  __syncthreads();
  int w=t>>6, l15=t&15, g=(t&63)>>4;
  f32x4 acc[2][8];
  #pragma unroll
  for (int i=0;i<2;i++){
    #pragma unroll
    for (int j=0;j<8;j++) acc[i][j] = (f32x4){0.f,0.f,0.f,0.f};
  }
  #pragma unroll
  for (int kk=0; kk<2; kk++){
    bf16x8 a0h = *(const bf16x8*)&xth[(32*w + l15)*72 + 32*kk + 8*g];
    bf16x8 a0l = *(const bf16x8*)&xtl[(32*w + l15)*72 + 32*kk + 8*g];
    bf16x8 a1h = *(const bf16x8*)&xth[(32*w + 16 + l15)*72 + 32*kk + 8*g];
    bf16x8 a1l = *(const bf16x8*)&xtl[(32*w + 16 + l15)*72 + 32*kk + 8*g];
    #pragma unroll
    for (int tc=0; tc<8; tc++){
      bf16x8 bh = WF(WnTh, kk*8+tc, lane);
      bf16x8 bl = WF(WnTl, kk*8+tc, lane);
      acc[0][tc] = MFMA(a0h,bh,acc[0][tc]);
      acc[0][tc] = MFMA(a0h,bl,acc[0][tc]);
      acc[0][tc] = MFMA(a0l,bh,acc[0][tc]);
      acc[1][tc] = MFMA(a1h,bh,acc[1][tc]);
      acc[1][tc] = MFMA(a1h,bl,acc[1][tc]);
      acc[1][tc] = MFMA(a1l,bh,acc[1][tc]);
    }
  }
  #pragma unroll
  for (int tc=0; tc<8; tc++){
    int col = 16*tc + l15;
    float bv = bn[col];
    #pragma unroll
    for (int tr=0; tr<2; tr++){
      int row = rb + 32*w + 16*tr + 4*g;
      #pragma unroll
      for (int j=0;j<4;j++){
        float v = acc[tr][tc][j] + bv;
        h[(size_t)(row+j)*128 + col] = v>0.f? v : 0.f;
      }
    }
  }
}

// ---------------- fused xl/xr GEMMs ----------------
__global__ __launch_bounds__(256) void k_xlr(const float* __restrict__ h,
    const u16* __restrict__ WlTh, const u16* __restrict__ WlTl,
    const u16* __restrict__ WrTh, const u16* __restrict__ WrTl,
    const float* __restrict__ bl, const float* __restrict__ br,
    float* __restrict__ xl, float* __restrict__ xr){
  __shared__ u16 hth[64*136], htl[64*136];
  int rb = blockIdx.x*64, t=threadIdx.x, lane=t&63;
  { int r = t>>2, q = t&3;
    const f32x4* s = (const f32x4*)(h + (size_t)(rb+r)*128 + q*32);
    #pragma unroll
    for (int i=0;i<8;i++){
      f32x4 v = s[i];
      u16x4 oh, ol;
      #pragma unroll
      for (int j=0;j<4;j++){ u16 hh,ll; splitf(v[j],hh,ll); oh[j]=hh; ol[j]=ll; }
      *(u16x4*)&hth[r*136 + q*32 + 4*i] = oh;
      *(u16x4*)&htl[r*136 + q*32 + 4*i] = ol;
    }
  }
  __syncthreads();
  int w=t>>6, l15=t&15, g=(t&63)>>4;
  #pragma unroll
  for (int side=0; side<2; side++){
    const u16* WTh = side? WrTh : WlTh;
    const u16* WTl = side? WrTl : WlTl;
    const float* bs = side? br : bl;
    float* out = side? xr : xl;
    f32x4 acc[8];
    #pragma unroll
    for (int j=0;j<8;j++) acc[j] = (f32x4){0.f,0.f,0.f,0.f};
    #pragma unroll
    for (int kk=0; kk<4; kk++){
      bf16x8 ah = *(const bf16x8*)&hth[(16*w + l15)*136 + 32*kk + 8*g];
      bf16x8 al = *(const bf16x8*)&htl[(16*w + l15)*136 + 32*kk + 8*g];
      #pragma unroll
      for (int tc=0; tc<8; tc++){
        bf16x8 bh = WF(WTh, kk*8+tc, lane);
        bf16x8 bl_ = WF(WTl, kk*8+tc, lane);
        acc[tc] = MFMA(ah,bh,acc[tc]);
        acc[tc] = MFMA(ah,bl_,acc[tc]);
        acc[tc] = MFMA(al,bh,acc[tc]);
      }
    }
    #pragma unroll
    for (int tc=0; tc<8; tc++){
      int col = 16*tc + l15;
      float bv = bs[col];
      #pragma unroll
      for (int j=0;j<4;j++)
        out[(size_t)(rb + 16*w + 4*g + j)*128 + col] = acc[tc][j] + bv;
    }
  }
}

// ---------------- fused edge kernel: We staged in LDS (shared by 4 waves) ----------------
__global__ __launch_bounds__(256) void k_edge(
    const float* __restrict__ easf, const u16* __restrict__ Wepfh, const u16* __restrict__ Wepfl,
    const float* __restrict__ bep,
    const u16* __restrict__ Wefh, const u16* __restrict__ Wefl, const float* __restrict__ attg,
    const float* __restrict__ xl, const float* __restrict__ xr,
    const int* __restrict__ srcs_s,
    float* __restrict__ logit_s)
{
  __shared__ u16 lWh[16384], lWl[16384];   // We fragments, 32 KB each
  int t = threadIdx.x, eb = blockIdx.x*64;
  int w=t>>6, lane=t&63, l15=t&15, g=(t&63)>>4;
  int eloc = 16*w + l15;

  // stage We hi/lo into LDS (coalesced, 16B per thread per iter)
  #pragma unroll
  for (int i=0;i<8;i++){
    int slot = t + 256*i;
    *(bf16x8*)&lWh[slot*8] = *(const bf16x8*)&Wefh[slot*8];
    *(bf16x8*)&lWl[slot*8] = *(const bf16x8*)&Wefl[slot*8];
  }
  __syncthreads();   // only barrier: stage complete

  // src/dst; issue random xl gathers FIRST (longest latency)
  int pk = srcs_s[eb + eloc];
  int sn = pk & 0xFFFF, dn = pk >> 16;
  f32x4 ga[8];
  #pragma unroll
  for (int tr=0; tr<8; tr++)
    ga[tr] = *(const f32x4*)(xl + (size_t)sn*128 + 16*tr + 4*g);

  // coalesced edge-attr fragment (pre-permuted)
  const float* ep = easf + (size_t)blockIdx.x*2048 + t*8;
  f32x4 ev0 = *(const f32x4*)ep;
  f32x4 ev1 = *(const f32x4*)(ep+4);
  bf16x8 ebh, ebl;
  #pragma unroll
  for (int j=0;j<4;j++){
    u16 hh,ll;
    splitf(ev0[j],hh,ll); ebh[j]=(short)hh; ebl[j]=(short)ll;
    splitf(ev1[j],hh,ll); ebh[4+j]=(short)hh; ebl[4+j]=(short)ll;
  }

  // GEMM1: e_pre[ch][edge] = Wep^T . ea^T  (Wep from global, coalesced)
  f32x4 a1[8];
  #pragma unroll
  for (int i=0;i<8;i++) a1[i] = (f32x4){0.f,0.f,0.f,0.f};
  #pragma unroll
  for (int tr=0; tr<8; tr++){
    bf16x8 wh = WF(Wepfh, tr, lane);
    bf16x8 wl = WF(Wepfl, tr, lane);
    a1[tr] = MFMA(wh,ebh,a1[tr]);
    a1[tr] = MFMA(wh,ebl,a1[tr]);
    a1[tr] = MFMA(wl,ebh,a1[tr]);
  }
  // bias + relu -> eval
  float eval[8][4];
  #pragma unroll
  for (int tr=0; tr<8; tr++){
    f32x4 bp = *(const f32x4*)(bep + 16*tr + 4*g);
    #pragma unroll
    for (int j=0;j<4;j++){
      float v = a1[tr][j] + bp[j];
      eval[tr][j] = v>0.f? v : 0.f;
    }
  }

  // xr gathers (dst-sorted -> cache-friendly)
  f32x4 gs[8];
  #pragma unroll
  for (int tr=0; tr<8; tr++){
    f32x4 b = *(const f32x4*)(xr + (size_t)dn*128 + 16*tr + 4*g);
    gs[tr] = ga[tr] + b;
  }

  // GEMM2: xe[ch][edge] = We^T . e ; A from LDS, B via in-wave shuffles
  f32x4 acc[8];
  #pragma unroll
  for (int i=0;i<8;i++) acc[i] = (f32x4){0.f,0.f,0.f,0.f};
  int lA = l15 + 32*(g&1);
  int lB = lA + 16;
  bool hiT = (g>>1) & 1;
  #pragma unroll
  for (int kk=0; kk<4; kk++){
    float bv[8];
    #pragma unroll
    for (int j=0;j<4;j++){
      float s0 = __shfl(eval[2*kk][j],   lA);
      float s1 = __shfl(eval[2*kk+1][j], lA);
      bv[j] = hiT? s1 : s0;
      float s2 = __shfl(eval[2*kk][j],   lB);
      float s3 = __shfl(eval[2*kk+1][j], lB);
      bv[4+j] = hiT? s3 : s2;
    }
    bf16x8 B2h, B2l;
    #pragma unroll
    for (int j=0;j<8;j++){
      u16 hh,ll; splitf(bv[j],hh,ll);
      B2h[j]=(short)hh; B2l[j]=(short)ll;
    }
    #pragma unroll
    for (int tr=0; tr<8; tr++){
      bf16x8 Ah = *(const bf16x8*)&lWh[(((kk*8+tr)<<6) + lane)*8];
      bf16x8 Al = *(const bf16x8*)&lWl[(((kk*8+tr)<<6) + lane)*8];
      acc[tr] = MFMA(Ah,B2h,acc[tr]);
      acc[tr] = MFMA(Ah,B2l,acc[tr]);
      acc[tr] = MFMA(Al,B2h,acc[tr]);
    }
  }

  // logits: att . leaky_relu(gs + xe); sequential write (sorted order)
  { float s0=0.f, s1=0.f;
    #pragma unroll
    for (int tr=0; tr<8; tr++){
      f32x4 at = *(const f32x4*)(attg + 16*tr + 4*g);
      #pragma unroll
      for (int j=0;j<4;j++){
        float m = acc[tr][j] + gs[tr][j];
        m = m>0.f ? m : 0.2f*m;
        if (tr < 4) s0 += at[j]*m; else s1 += at[j]*m;
      }
    }
    s0 += __shfl_xor(s0,16); s0 += __shfl_xor(s0,32);
    s1 += __shfl_xor(s1,16); s1 += __shfl_xor(s1,32);
    if (g==0) ((f32x2*)logit_s)[eb + eloc] = (f32x2){s0, s1};
  }
}

// ---------------- CSR softmax + aggregate + LN: 2 waves per node ----------------
__global__ __launch_bounds__(256) void k_aggr(
    const float* __restrict__ xl, const float* __restrict__ logit_s,
    const int* __restrict__ srcs, const int* __restrict__ off,
    const float* __restrict__ gbias, const float* __restrict__ lng, const float* __restrict__ lnb,
    float* __restrict__ h)
{
  __shared__ float ssum[2][2], svar[2][2];
  int t = threadIdx.x;
  int w = t>>6, l = t&63;
  int node2 = w>>1, sub = w&1;        // 2 nodes/block, 2 waves/node
  int n = blockIdx.x*2 + node2;
  int base = off[n], deg = off[n+1] - base;
  const f32x2* lg = (const f32x2*)logit_s;
  // softmax stats for this wave's head (sub)
  float m = -1e30f;
  for (int j=l; j<deg; j+=64){ f32x2 v = lg[base+j]; m = fmaxf(m, sub? v[1] : v[0]); }
  #pragma unroll
  for (int mk=1; mk<64; mk<<=1) m = fmaxf(m, __shfl_xor(m, mk));
  float s = 0.f;
  for (int j=l; j<deg; j+=64){ f32x2 v = lg[base+j]; s += __expf((sub? v[1]:v[0]) - m); }
  #pragma unroll
  for (int mk=1; mk<64; mk<<=1) s += __shfl_xor(s, mk);
  float r = s>0.f? 1.f/s : 0.f;
  // aggregation: channel c = sub*64 + l (one gather per iter)
  int c = sub*64 + l;
  float a = 0.f;
  for (int j=0;j<deg;j++){
    int sj = srcs[base+j] & 0xFFFF;
    f32x2 v = lg[base+j];
    float wgt = __expf((sub? v[1]:v[0]) - m) * r;
    a += wgt * xl[(size_t)sj*128 + c];
  }
  // residual + bias, then LN across 128 channels (2 waves)
  float tv = h[(size_t)n*128 + c] + a + gbias[c];
  float sm = tv;
  #pragma unroll
  for (int mk=1; mk<64; mk<<=1) sm += __shfl_xor(sm, mk);
  if (l==0) ssum[node2][sub] = sm;
  __syncthreads();
  float mean = (ssum[node2][0] + ssum[node2][1]) * (1.f/128.f);
  float d = tv - mean;
  float vs = d*d;
  #pragma unroll
  for (int mk=1; mk<64; mk<<=1) vs += __shfl_xor(vs, mk);
  if (l==0) svar[node2][sub] = vs;
  __syncthreads();
  float var = (svar[node2][0] + svar[node2][1]) * (1.f/128.f);
  float inv = rsqrtf(var + 1e-5f);
  h[(size_t)n*128 + c] = d*inv*lng[c] + lnb[c];
}

// ---------------- node logits ----------------
__global__ __launch_bounds__(256) void k_nl(const float* __restrict__ h,
    const u16* __restrict__ aW1Th, const u16* __restrict__ aW1Tl,
    const float* __restrict__ ab1, const float* __restrict__ aW2, const float* __restrict__ ab2,
    float* __restrict__ nl){
  __shared__ u16 hth[64*136], htl[64*136];
  int rb = blockIdx.x*64, t=threadIdx.x, lane=t&63;
  { int r = t>>2, q = t&3;
    const f32x4* s = (const f32x4*)(h + (size_t)(rb+r)*128 + q*32);
    #pragma unroll
    for (int i=0;i<8;i++){
      f32x4 v = s[i];
      u16x4 oh, ol;
      #pragma unroll
      for (int j=0;j<4;j++){ u16 hh,ll; splitf(v[j],hh,ll); oh[j]=hh; ol[j]=ll; }
      *(u16x4*)&hth[r*136 + q*32 + 4*i] = oh;
      *(u16x4*)&htl[r*136 + q*32 + 4*i] = ol;
    }
  }
  __syncthreads();
  int w=t>>6, l15=t&15, g=(t&63)>>4;
  f32x4 acc[8];
  #pragma unroll
  for (int j=0;j<8;j++) acc[j] = (f32x4){0.f,0.f,0.f,0.f};
  #pragma unroll
  for (int kk=0; kk<4; kk++){
    bf16x8 ah = *(const bf16x8*)&hth[(16*w + l15)*136 + 32*kk + 8*g];
    bf16x8 al = *(const bf16x8*)&htl[(16*w + l15)*136 + 32*kk + 8*g];
    #pragma unroll
    for (int tc=0; tc<8; tc++){
      bf16x8 bh = WF(aW1Th, kk*8+tc, lane);
      bf16x8 bl_ = WF(aW1Tl, kk*8+tc, lane);
      acc[tc] = MFMA(ah,bh,acc[tc]);
      acc[tc] = MFMA(ah,bl_,acc[tc]);
      acc[tc] = MFMA(al,bh,acc[tc]);
    }
  }
  float s[4] = {0.f,0.f,0.f,0.f};
  #pragma unroll
  for (int tc=0; tc<8; tc++){
    int col = 16*tc + l15;
    float a2 = aW2[col];
    float b1 = ab1[col];
    #pragma unroll
    for (int j=0;j<4;j++){
      float v = acc[tc][j] + b1;
      v = v>0.f? v : 0.f;
      s[j] += v*a2;
    }
  }
  #pragma unroll
  for (int mk=1; mk<16; mk<<=1){
    #pragma unroll
    for (int j=0;j<4;j++) s[j] += __shfl_xor(s[j], mk);
  }
  if (l15==0){
    float b2 = ab2[0];
    #pragma unroll
    for (int j=0;j<4;j++) nl[rb + 16*w + 4*g + j] = s[j] + b2;
  }
}

// ---------------- per-graph mean/max/min, 2-stage ----------------
__global__ __launch_bounds__(256) void k_gf1(const float* __restrict__ h, float* __restrict__ gfp){
  __shared__ float red[3][2][128];
  int b = blockIdx.x;             // 128 blocks: (graph g, slice sl of 256 rows)
  int g = b>>3, sl = b&7;
  int t = threadIdx.x; int c = t&127, hh = t>>7;
  const float* p = h + (size_t)g*2048*128 + (size_t)(sl*256 + hh*128)*128 + c;
  float s=0.f, mx=-1e30f, mn=1e30f;
  for (int i=0;i<128;i++){ float v = p[(size_t)i*128]; s+=v; mx=fmaxf(mx,v); mn=fminf(mn,v); }
  red[0][hh][c]=s; red[1][hh][c]=mx; red[2][hh][c]=mn;
  __syncthreads();
  if (hh==0){
    gfp[b*384 + c]       = s + red[0][1][c];
    gfp[b*384 + 128 + c] = fmaxf(mx, red[1][1][c]);
    gfp[b*384 + 256 + c] = fminf(mn, red[2][1][c]);
  }
}
__global__ void k_gf2(const float* __restrict__ gfp, float* __restrict__ gf){
  int g = blockIdx.x, c = threadIdx.x;  // 16 x 128
  float S=0.f, MX=-1e30f, MN=1e30f;
  for (int k=0;k<8;k++){
    const float* q = gfp + (g*8+k)*384;
    S += q[c]; MX=fmaxf(MX,q[128+c]); MN=fminf(MN,q[256+c]);
  }
  gf[g*384+c]=S*(1.f/2048.f); gf[g*384+128+c]=MX; gf[g*384+256+c]=MN;
}

// ---------------- per-graph argmax / log_softmax / entropy ----------------
__global__ __launch_bounds__(256) void k_action(const float* __restrict__ nl, float* __restrict__ out){
  __shared__ float vmax[256]; __shared__ int vidx[256];
  __shared__ float r1[256], r2[256];
  int g = blockIdx.x, t = threadIdx.x;
  const float* p = nl + g*2048;
  float mx = -1e30f; int mi = 0;
  for (int i=t;i<2048;i+=256){ float v=p[i]; if (v>mx){mx=v;mi=i;} }
  vmax[t]=mx; vidx[t]=mi; __syncthreads();
  for (int s=128;s>0;s>>=1){
    if (t<s){
      float vo=vmax[t+s]; int io=vidx[t+s];
      if (vo > vmax[t] || (vo==vmax[t] && io<vidx[t])){ vmax[t]=vo; vidx[t]=io; }
    }
    __syncthreads();
  }
  float M = vmax[0]; int A = vidx[0];
  float s1=0.f, sl=0.f;
  for (int i=t;i<2048;i+=256){ float d=p[i]-M; float e=__expf(d); s1+=e; sl+=d*e; }
  r1[t]=s1; r2[t]=sl; __syncthreads();
  for (int s=128;s>0;s>>=1){ if (t<s){ r1[t]+=r1[t+s]; r2[t]+=r2[t+s]; } __syncthreads(); }
  if (t==0){
    float S=r1[0], SL=r2[0];
    out[g]      = (float)A;
    out[16+g]   = -logf(S);
    out[32+g]   = logf(S) - SL/S;
  }
}

// ---------------- value head ----------------
__global__ void k_value(const float* __restrict__ gf,
    const float* __restrict__ gnW, const float* __restrict__ gnb,
    const float* __restrict__ gng, const float* __restrict__ gnbeta,
    const float* __restrict__ cW1, const float* __restrict__ cb1,
    const float* __restrict__ cW2, const float* __restrict__ cb2,
    float* __restrict__ out){
  __shared__ float gfL[384]; __shared__ float u[128]; __shared__ float red[128];
  int g = blockIdx.x, t = threadIdx.x;   // 128 threads
  for (int i=t;i<384;i+=128) gfL[i] = gf[g*384+i];
  __syncthreads();
  float acc = gnb[t];
  for (int k=0;k<384;k++) acc += gfL[k]*gnW[k*128+t];
  acc = fmaxf(acc, 0.f);
  red[t]=acc; __syncthreads();
  for (int s=64;s>0;s>>=1){ if(t<s) red[t]+=red[t+s]; __syncthreads(); }
  float mean = red[0]*(1.f/128.f); __syncthreads();
  float dd = acc-mean; red[t]=dd*dd; __syncthreads();
  for (int s=64;s>0;s>>=1){ if(t<s) red[t]+=red[t+s]; __syncthreads(); }
  float var = red[0]*(1.f/128.f); __syncthreads();
  u[t] = dd*rsqrtf(var + 1e-5f)*gng[t] + gnbeta[t];
  __syncthreads();
  float a2 = cb1[t];
  for (int k=0;k<128;k++) a2 += u[k]*cW1[k*128+t];
  a2 = fmaxf(a2, 0.f);
  red[t] = a2*cW2[t]; __syncthreads();
  for (int s=64;s>0;s>>=1){ if(t<s) red[t]+=red[t+s]; __syncthreads(); }
  if (t==0) out[48+g] = red[0] + cb2[0];
}

// ---------------- launch ----------------
extern "C" void kernel_launch(void* const* d_in, const int* in_sizes, int n_in,
                              void* d_out, int out_size, void* d_ws, size_t ws_size,
                              hipStream_t stream) {
  (void)in_sizes; (void)n_in; (void)out_size; (void)ws_size;
  const float* x    = (const float*)d_in[0];
  const float* ea   = (const float*)d_in[1];
  const int*   ei   = (const int*)d_in[2];
  const float* Wn   = (const float*)d_in[4];
  const float* bn   = (const float*)d_in[5];
  const float* Wep  = (const float*)d_in[6];
  const float* bep  = (const float*)d_in[7];
  const float* gWl  = (const float*)d_in[8];
  const float* gbl  = (const float*)d_in[9];
  const float* gWr  = (const float*)d_in[10];
  const float* gbr  = (const float*)d_in[11];
  const float* gWe  = (const float*)d_in[12];
  const float* gatt = (const float*)d_in[13];
  const float* gbias= (const float*)d_in[14];
  const float* lng  = (const float*)d_in[15];
  const float* lnb  = (const float*)d_in[16];
  const float* gnW  = (const float*)d_in[17];
  const float* gnb  = (const float*)d_in[18];
  const float* gng  = (const float*)d_in[19];
  const float* gnbt = (const float*)d_in[20];
  const float* aW1  = (const float*)d_in[25];
  const float* ab1  = (const float*)d_in[26];
  const float* aW2  = (const float*)d_in[27];
  const float* ab2  = (const float*)d_in[28];
  const float* cW1  = (const float*)d_in[29];
  const float* cb1  = (const float*)d_in[30];
  const float* cW2  = (const float*)d_in[31];
  const float* cb2  = (const float*)d_in[32];
  float* out = (float*)d_out;

  char* W = (char*)d_ws;
  float* h      = (float*)(W + 0);
  float* xl     = (float*)(W + 16777216);
  float* xr     = (float*)(W + 33554432);
  float* logit  = (float*)(W + 50331648);
  int*   srcs   = (int*)  (W + 54525952);
  int*   eids   = (int*)  (W + 56623104);
  int*   cnt    = (int*)  (W + 58720256);
  int*   off    = (int*)  (W + 58851328);
  int*   cur    = (int*)  (W + 58982656);
  float* nl     = (float*)(W + 59113728);
  float* gf     = (float*)(W + 59244800);
  u16*   WnTh   = (u16*)  (W + 59269376);
  u16*   WnTl   = WnTh  + 8192;
  u16*   WepTh  = WnTl  + 8192;
  u16*   WepTl  = WepTh + 4096;
  u16*   WlTh   = WepTl + 4096;
  u16*   WlTl   = WlTh  + 49152;
  u16*   WrTh   = WlTl  + 49152;
  u16*   WrTl   = WrTh  + 49152;
  u16*   WeTh   = WrTl  + 49152;
  u16*   WeTl   = WeTh  + 49152;
  u16*   aW1Th  = WeTl  + 49152;
  u16*   aW1Tl  = aW1Th + 16384;
  float* gfp    = (float*)(W + 59973888);   // 128*384*4 = 196.6 KB (gap before easf)
  float* easf   = (float*)(W + 60817408);   // E*32 fp32 = 67.1 MB

  (void)hipMemsetAsync(cnt, 0, NN*sizeof(int), stream);
  k_hist<<<NE/256, 256, 0, stream>>>(ei + NE, cnt);
  k_scan<<<1, 1024, 0, stream>>>(cnt, off, cur);
  k_scatter<<<NE/256, 256, 0, stream>>>(ei, cur, srcs, eids);
  k_presort<<<NE/64, 256, 0, stream>>>(ea, eids, easf);

  TP tp;
  tp.s[0]=Wn;  tp.dh[0]=WnTh;  tp.dl[0]=WnTl;  tp.K[0]=64;
  tp.s[1]=Wep; tp.dh[1]=WepTh; tp.dl[1]=WepTl; tp.K[1]=32;
  for (int l=0;l<3;l++){
    tp.s[2+l]=gWl + l*16384; tp.dh[2+l]=WlTh + l*16384; tp.dl[2+l]=WlTl + l*16384; tp.K[2+l]=128;
    tp.s[5+l]=gWr + l*16384; tp.dh[5+l]=WrTh + l*16384; tp.dl[5+l]=WrTl + l*16384; tp.K[5+l]=128;
    tp.s[8+l]=gWe + l*16384; tp.dh[8+l]=WeTh + l*16384; tp.dl[8+l]=WeTl + l*16384; tp.K[8+l]=128;
  }
  tp.s[11]=aW1; tp.dh[11]=aW1Th; tp.dl[11]=aW1Tl; tp.K[11]=128;
  k_transpose<<<12, 256, 0, stream>>>(tp);

  k_h0<<<NN/128, 256, 0, stream>>>(x, WnTh, WnTl, bn, h);

  for (int l=0; l<3; l++){
    k_xlr<<<NN/64, 256, 0, stream>>>(h, WlTh + l*16384, WlTl + l*16384,
                                     WrTh + l*16384, WrTl + l*16384,
                                     gbl + l*128, gbr + l*128, xl, xr);
    k_edge<<<NE/64, 256, 0, stream>>>(easf, WepTh, WepTl, bep,
                                      WeTh + l*16384, WeTl + l*16384, gatt + l*128,
                                      xl, xr, srcs, logit);
    k_aggr<<<NN/2, 256, 0, stream>>>(xl, logit, srcs, off,
                                     gbias + l*128, lng + l*128, lnb + l*128, h);
  }

  k_nl<<<NN/64, 256, 0, stream>>>(h, aW1Th, aW1Tl, ab1, aW2, ab2, nl);
  k_gf1<<<128, 256, 0, stream>>>(h, gfp);
  k_gf2<<<NG, 128, 0, stream>>>(gfp, gf);
  k_action<<<NG, 256, 0, stream>>>(nl, out);
  k_value<<<NG, 128, 0, stream>>>(gf, gnW, gnb, gng, gnbt,
                                  cW1, cb1, cW2, cb2, out);
}

// Round 10
// 930.677 us; speedup vs baseline: 1.2503x; 1.2503x over previous
//
#include <hip/hip_runtime.h>

typedef unsigned short u16;
typedef unsigned int u32;
typedef __attribute__((ext_vector_type(8))) short bf16x8;
typedef __attribute__((ext_vector_type(4))) float f32x4;
typedef __attribute__((ext_vector_type(2))) float f32x2;
typedef __attribute__((ext_vector_type(4))) u16 u16x4;

#define NN 32768
#define NE 524288
#define NG 16

__device__ __forceinline__ float bf2f(u16 v){ u32 u=((u32)v)<<16; float f; __builtin_memcpy(&f,&u,4); return f; }
__device__ __forceinline__ u16 f2bf(float f){ u32 u; __builtin_memcpy(&u,&f,4); return (u16)((u + 0x7fffu + ((u>>16)&1u))>>16); }
__device__ __forceinline__ void splitf(float v, u16& hi, u16& lo){
  u16 h = f2bf(v); hi = h; lo = f2bf(v - bf2f(h));
}
__device__ __forceinline__ f32x4 MFMA(bf16x8 a, bf16x8 b, f32x4 c){
  return __builtin_amdgcn_mfma_f32_16x16x32_bf16(a,b,c,0,0,0);
}
// fragment-major weight access: chunk c = kk*8 + tile, lane-coalesced 16B/lane
__device__ __forceinline__ bf16x8 WF(const u16* W, int c, int lane){
  return *(const bf16x8*)&W[((c<<6) + lane)*8];
}

// ---------------- sort stack ----------------
__global__ __launch_bounds__(256) void k_hist(const int* __restrict__ dst, int* __restrict__ cnt){
  int e = blockIdx.x*256 + threadIdx.x;
  if (e < NE) atomicAdd(&cnt[dst[e]], 1);
}

__global__ __launch_bounds__(1024) void k_scan(const int* __restrict__ cnt, int* __restrict__ off, int* __restrict__ cur){
  __shared__ int sums[1024];
  int t = threadIdx.x;
  int base = t*32; int s = 0;
  for (int i=0;i<32;i++) s += cnt[base+i];
  sums[t] = s; __syncthreads();
  for (int d=1; d<1024; d<<=1){
    int v = (t>=d)? sums[t-d] : 0; __syncthreads();
    sums[t] += v; __syncthreads();
  }
  int excl = (t==0)?0:sums[t-1];
  for (int i=0;i<32;i++){ int idx=base+i; off[idx]=excl; cur[idx]=excl; excl += cnt[idx]; }
  if (t==1023) off[NN] = excl;
}

__global__ __launch_bounds__(256) void k_scatter(const int* __restrict__ ei, int* __restrict__ cur,
                                                 int* __restrict__ srcs, int* __restrict__ eids){
  int e = blockIdx.x*256 + threadIdx.x;
  if (e < NE){
    int d = ei[NE + e];
    int p = atomicAdd(&cur[d], 1);
    srcs[p] = ei[e] | (d<<16);
    eids[p] = e;
  }
}

// gather ea rows into the exact fragment order k_edge consumes
__global__ __launch_bounds__(256) void k_presort(const float* __restrict__ ea, const int* __restrict__ eids,
                                                 float* __restrict__ easf){
  int t = threadIdx.x;
  int w = t>>6, lam = t&63;
  int p = blockIdx.x*64 + 16*w + (lam&15);
  int e = eids[p];
  f32x4 v0 = *(const f32x4*)(ea + (size_t)e*32 + (lam>>4)*8);
  f32x4 v1 = *(const f32x4*)(ea + (size_t)e*32 + (lam>>4)*8 + 4);
  float* d = easf + (size_t)blockIdx.x*2048 + t*8;
  *(f32x4*)d = v0; *(f32x4*)(d+4) = v1;
}

// ---------------- weight -> fragment-major hi/lo ----------------
struct TP { const float* s[12]; u16* dh[12]; u16* dl[12]; int K[12]; };
__global__ __launch_bounds__(256) void k_transpose(TP tp){
  int b = blockIdx.x;
  const float* s = tp.s[b]; u16* dh = tp.dh[b]; u16* dl = tp.dl[b]; int K = tp.K[b];
  int nslots = K*16;
  for (int i = threadIdx.x; i < nslots; i += 256){
    int c = i>>6, lam = i&63;
    int kk = c>>3, tc = c&7;
    int srow = 32*kk + 8*(lam>>4);
    int scol = 16*tc + (lam&15);
    #pragma unroll
    for (int j=0;j<8;j++){
      float v = s[(size_t)(srow+j)*128 + scol];
      u16 h, l; splitf(v, h, l);
      dh[(size_t)i*8 + j] = h; dl[(size_t)i*8 + j] = l;
    }
  }
}

// ---------------- h0 = relu(x @ Wn + bn) ----------------
__global__ __launch_bounds__(256) void k_h0(const float* __restrict__ x,
    const u16* __restrict__ WnTh, const u16* __restrict__ WnTl,
    const float* __restrict__ bn, float* __restrict__ h){
  __shared__ u16 xth[128*72], xtl[128*72];
  int rb = blockIdx.x*128, t = threadIdx.x, lane = t&63;
  { int r = t & 127, p = t >> 7;
    const f32x4* s = (const f32x4*)(x + (size_t)(rb+r)*64 + p*32);
    #pragma unroll
    for (int i=0;i<8;i++){
      f32x4 v = s[i];
      u16x4 oh, ol;
      #pragma unroll
      for (int j=0;j<4;j++){ u16 hh,ll; splitf(v[j],hh,ll); oh[j]=hh; ol[j]=ll; }
      *(u16x4*)&xth[r*72 + p*32 + 4*i] = oh;
      *(u16x4*)&xtl[r*72 + p*32 + 4*i] = ol;
    }
  }
  __syncthreads();
  int w=t>>6, l15=t&15, g=(t&63)>>4;
  f32x4 acc[2][8];
  #pragma unroll
  for (int i=0;i<2;i++){
    #pragma unroll
    for (int j=0;j<8;j++) acc[i][j] = (f32x4){0.f,0.f,0.f,0.f};
  }
  #pragma unroll
  for (int kk=0; kk<2; kk++){
    bf16x8 a0h = *(const bf16x8*)&xth[(32*w + l15)*72 + 32*kk + 8*g];
    bf16x8 a0l = *(const bf16x8*)&xtl[(32*w + l15)*72 + 32*kk + 8*g];
    bf16x8 a1h = *(const bf16x8*)&xth[(32*w + 16 + l15)*72 + 32*kk + 8*g];
    bf16x8 a1l = *(const bf16x8*)&xtl[(32*w + 16 + l15)*72 + 32*kk + 8*g];
    #pragma unroll
    for (int tc=0; tc<8; tc++){
      bf16x8 bh = WF(WnTh, kk*8+tc, lane);
      bf16x8 bl = WF(WnTl, kk*8+tc, lane);
      acc[0][tc] = MFMA(a0h,bh,acc[0][tc]);
      acc[0][tc] = MFMA(a0h,bl,acc[0][tc]);
      acc[0][tc] = MFMA(a0l,bh,acc[0][tc]);
      acc[1][tc] = MFMA(a1h,bh,acc[1][tc]);
      acc[1][tc] = MFMA(a1h,bl,acc[1][tc]);
      acc[1][tc] = MFMA(a1l,bh,acc[1][tc]);
    }
  }
  #pragma unroll
  for (int tc=0; tc<8; tc++){
    int col = 16*tc + l15;
    float bv = bn[col];
    #pragma unroll
    for (int tr=0; tr<2; tr++){
      int row = rb + 32*w + 16*tr + 4*g;
      #pragma unroll
      for (int j=0;j<4;j++){
        float v = acc[tr][tc][j] + bv;
        h[(size_t)(row+j)*128 + col] = v>0.f? v : 0.f;
      }
    }
  }
}

// ---------------- fused xl/xr GEMMs ----------------
__global__ __launch_bounds__(256) void k_xlr(const float* __restrict__ h,
    const u16* __restrict__ WlTh, const u16* __restrict__ WlTl,
    const u16* __restrict__ WrTh, const u16* __restrict__ WrTl,
    const float* __restrict__ bl, const float* __restrict__ br,
    float* __restrict__ xl, float* __restrict__ xr){
  __shared__ u16 hth[64*136], htl[64*136];
  int rb = blockIdx.x*64, t=threadIdx.x, lane=t&63;
  { int r = t>>2, q = t&3;
    const f32x4* s = (const f32x4*)(h + (size_t)(rb+r)*128 + q*32);
    #pragma unroll
    for (int i=0;i<8;i++){
      f32x4 v = s[i];
      u16x4 oh, ol;
      #pragma unroll
      for (int j=0;j<4;j++){ u16 hh,ll; splitf(v[j],hh,ll); oh[j]=hh; ol[j]=ll; }
      *(u16x4*)&hth[r*136 + q*32 + 4*i] = oh;
      *(u16x4*)&htl[r*136 + q*32 + 4*i] = ol;
    }
  }
  __syncthreads();
  int w=t>>6, l15=t&15, g=(t&63)>>4;
  #pragma unroll
  for (int side=0; side<2; side++){
    const u16* WTh = side? WrTh : WlTh;
    const u16* WTl = side? WrTl : WlTl;
    const float* bs = side? br : bl;
    float* out = side? xr : xl;
    f32x4 acc[8];
    #pragma unroll
    for (int j=0;j<8;j++) acc[j] = (f32x4){0.f,0.f,0.f,0.f};
    #pragma unroll
    for (int kk=0; kk<4; kk++){
      bf16x8 ah = *(const bf16x8*)&hth[(16*w + l15)*136 + 32*kk + 8*g];
      bf16x8 al = *(const bf16x8*)&htl[(16*w + l15)*136 + 32*kk + 8*g];
      #pragma unroll
      for (int tc=0; tc<8; tc++){
        bf16x8 bh = WF(WTh, kk*8+tc, lane);
        bf16x8 bl_ = WF(WTl, kk*8+tc, lane);
        acc[tc] = MFMA(ah,bh,acc[tc]);
        acc[tc] = MFMA(ah,bl_,acc[tc]);
        acc[tc] = MFMA(al,bh,acc[tc]);
      }
    }
    #pragma unroll
    for (int tc=0; tc<8; tc++){
      int col = 16*tc + l15;
      float bv = bs[col];
      #pragma unroll
      for (int j=0;j<4;j++)
        out[(size_t)(rb + 16*w + 4*g + j)*128 + col] = acc[tc][j] + bv;
    }
  }
}

// ---------------- fused edge kernel: We staged in LDS (shared by 4 waves) ----------------
__global__ __launch_bounds__(256) void k_edge(
    const float* __restrict__ easf, const u16* __restrict__ Wepfh, const u16* __restrict__ Wepfl,
    const float* __restrict__ bep,
    const u16* __restrict__ Wefh, const u16* __restrict__ Wefl, const float* __restrict__ attg,
    const float* __restrict__ xl, const float* __restrict__ xr,
    const int* __restrict__ srcs_s,
    float* __restrict__ logit_s)
{
  __shared__ u16 lWh[16384], lWl[16384];   // We fragments, 32 KB each
  int t = threadIdx.x, eb = blockIdx.x*64;
  int w=t>>6, lane=t&63, l15=t&15, g=(t&63)>>4;
  int eloc = 16*w + l15;

  // stage We hi/lo into LDS (coalesced, 16B per thread per iter)
  #pragma unroll
  for (int i=0;i<8;i++){
    int slot = t + 256*i;
    *(bf16x8*)&lWh[slot*8] = *(const bf16x8*)&Wefh[slot*8];
    *(bf16x8*)&lWl[slot*8] = *(const bf16x8*)&Wefl[slot*8];
  }
  __syncthreads();   // only barrier: stage complete

  // src/dst; issue random xl gathers FIRST (longest latency)
  int pk = srcs_s[eb + eloc];
  int sn = pk & 0xFFFF, dn = pk >> 16;
  f32x4 ga[8];
  #pragma unroll
  for (int tr=0; tr<8; tr++)
    ga[tr] = *(const f32x4*)(xl + (size_t)sn*128 + 16*tr + 4*g);

  // coalesced edge-attr fragment (pre-permuted)
  const float* ep = easf + (size_t)blockIdx.x*2048 + t*8;
  f32x4 ev0 = *(const f32x4*)ep;
  f32x4 ev1 = *(const f32x4*)(ep+4);
  bf16x8 ebh, ebl;
  #pragma unroll
  for (int j=0;j<4;j++){
    u16 hh,ll;
    splitf(ev0[j],hh,ll); ebh[j]=(short)hh; ebl[j]=(short)ll;
    splitf(ev1[j],hh,ll); ebh[4+j]=(short)hh; ebl[4+j]=(short)ll;
  }

  // GEMM1: e_pre[ch][edge] = Wep^T . ea^T  (Wep from global, coalesced)
  f32x4 a1[8];
  #pragma unroll
  for (int i=0;i<8;i++) a1[i] = (f32x4){0.f,0.f,0.f,0.f};
  #pragma unroll
  for (int tr=0; tr<8; tr++){
    bf16x8 wh = WF(Wepfh, tr, lane);
    bf16x8 wl = WF(Wepfl, tr, lane);
    a1[tr] = MFMA(wh,ebh,a1[tr]);
    a1[tr] = MFMA(wh,ebl,a1[tr]);
    a1[tr] = MFMA(wl,ebh,a1[tr]);
  }
  // bias + relu -> eval
  float eval[8][4];
  #pragma unroll
  for (int tr=0; tr<8; tr++){
    f32x4 bp = *(const f32x4*)(bep + 16*tr + 4*g);
    #pragma unroll
    for (int j=0;j<4;j++){
      float v = a1[tr][j] + bp[j];
      eval[tr][j] = v>0.f? v : 0.f;
    }
  }

  // xr gathers (dst-sorted -> cache-friendly)
  f32x4 gs[8];
  #pragma unroll
  for (int tr=0; tr<8; tr++){
    f32x4 b = *(const f32x4*)(xr + (size_t)dn*128 + 16*tr + 4*g);
    gs[tr] = ga[tr] + b;
  }

  // GEMM2: xe[ch][edge] = We^T . e ; A from LDS, B via in-wave shuffles
  f32x4 acc[8];
  #pragma unroll
  for (int i=0;i<8;i++) acc[i] = (f32x4){0.f,0.f,0.f,0.f};
  int lA = l15 + 32*(g&1);
  int lB = lA + 16;
  bool hiT = (g>>1) & 1;
  #pragma unroll
  for (int kk=0; kk<4; kk++){
    float bv[8];
    #pragma unroll
    for (int j=0;j<4;j++){
      float s0 = __shfl(eval[2*kk][j],   lA);
      float s1 = __shfl(eval[2*kk+1][j], lA);
      bv[j] = hiT? s1 : s0;
      float s2 = __shfl(eval[2*kk][j],   lB);
      float s3 = __shfl(eval[2*kk+1][j], lB);
      bv[4+j] = hiT? s3 : s2;
    }
    bf16x8 B2h, B2l;
    #pragma unroll
    for (int j=0;j<8;j++){
      u16 hh,ll; splitf(bv[j],hh,ll);
      B2h[j]=(short)hh; B2l[j]=(short)ll;
    }
    #pragma unroll
    for (int tr=0; tr<8; tr++){
      bf16x8 Ah = *(const bf16x8*)&lWh[(((kk*8+tr)<<6) + lane)*8];
      bf16x8 Al = *(const bf16x8*)&lWl[(((kk*8+tr)<<6) + lane)*8];
      acc[tr] = MFMA(Ah,B2h,acc[tr]);
      acc[tr] = MFMA(Ah,B2l,acc[tr]);
      acc[tr] = MFMA(Al,B2h,acc[tr]);
    }
  }

  // logits: att . leaky_relu(gs + xe); sequential write (sorted order)
  { float s0=0.f, s1=0.f;
    #pragma unroll
    for (int tr=0; tr<8; tr++){
      f32x4 at = *(const f32x4*)(attg + 16*tr + 4*g);
      #pragma unroll
      for (int j=0;j<4;j++){
        float m = acc[tr][j] + gs[tr][j];
        m = m>0.f ? m : 0.2f*m;
        if (tr < 4) s0 += at[j]*m; else s1 += at[j]*m;
      }
    }
    s0 += __shfl_xor(s0,16); s0 += __shfl_xor(s0,32);
    s1 += __shfl_xor(s1,16); s1 += __shfl_xor(s1,32);
    if (g==0) ((f32x2*)logit_s)[eb + eloc] = (f32x2){s0, s1};
  }
}

// ---------------- CSR softmax + aggregate + bias + residual + LayerNorm (1 wave/node, 4x unrolled) ----------------
__global__ __launch_bounds__(256) void k_aggr(
    const float* __restrict__ xl, const float* __restrict__ logit_s,
    const int* __restrict__ srcs, const int* __restrict__ off,
    const float* __restrict__ gbias, const float* __restrict__ lng, const float* __restrict__ lnb,
    float* __restrict__ h)
{
  int w = threadIdx.x>>6, l = threadIdx.x&63;
  int n = blockIdx.x*4 + w;
  int base = off[n], deg = off[n+1] - base;
  const f32x2* lg = (const f32x2*)logit_s;
  float m0=-1e30f, m1=-1e30f;
  for (int j=l; j<deg; j+=64){ f32x2 v = lg[base+j]; m0=fmaxf(m0,v[0]); m1=fmaxf(m1,v[1]); }
  #pragma unroll
  for (int mk=1; mk<64; mk<<=1){ m0=fmaxf(m0,__shfl_xor(m0,mk)); m1=fmaxf(m1,__shfl_xor(m1,mk)); }
  float s0=0.f, s1=0.f;
  for (int j=l; j<deg; j+=64){ f32x2 v = lg[base+j]; s0+=__expf(v[0]-m0); s1+=__expf(v[1]-m1); }
  #pragma unroll
  for (int mk=1; mk<64; mk<<=1){ s0+=__shfl_xor(s0,mk); s1+=__shfl_xor(s1,mk); }
  float r0 = s0>0.f? 1.f/s0 : 0.f;
  float r1 = s1>0.f? 1.f/s1 : 0.f;
  float a0=0.f, a1=0.f;
  int j = 0;
  for (; j+4<=deg; j+=4){
    int q0 = srcs[base+j]   & 0xFFFF;
    int q1 = srcs[base+j+1] & 0xFFFF;
    int q2 = srcs[base+j+2] & 0xFFFF;
    int q3 = srcs[base+j+3] & 0xFFFF;
    f32x2 v0 = lg[base+j], v1 = lg[base+j+1], v2 = lg[base+j+2], v3 = lg[base+j+3];
    const float* p0 = xl + (size_t)q0*128 + l;
    const float* p1 = xl + (size_t)q1*128 + l;
    const float* p2 = xl + (size_t)q2*128 + l;
    const float* p3 = xl + (size_t)q3*128 + l;
    float xa0 = p0[0], xb0 = p0[64];
    float xa1 = p1[0], xb1 = p1[64];
    float xa2 = p2[0], xb2 = p2[64];
    float xa3 = p3[0], xb3 = p3[64];
    float w00 = __expf(v0[0]-m0)*r0, w01 = __expf(v0[1]-m1)*r1;
    float w10 = __expf(v1[0]-m0)*r0, w11 = __expf(v1[1]-m1)*r1;
    float w20 = __expf(v2[0]-m0)*r0, w21 = __expf(v2[1]-m1)*r1;
    float w30 = __expf(v3[0]-m0)*r0, w31 = __expf(v3[1]-m1)*r1;
    a0 += w00*xa0; a1 += w01*xb0;
    a0 += w10*xa1; a1 += w11*xb1;
    a0 += w20*xa2; a1 += w21*xb2;
    a0 += w30*xa3; a1 += w31*xb3;
  }
  for (; j<deg; j++){
    int sj = srcs[base+j] & 0xFFFF;
    f32x2 v = lg[base+j];
    float w0 = __expf(v[0]-m0)*r0, w1 = __expf(v[1]-m1)*r1;
    a0 += w0 * xl[(size_t)sj*128 + l];
    a1 += w1 * xl[(size_t)sj*128 + 64 + l];
  }
  int c0=l, c1=64+l;
  float t0 = h[(size_t)n*128+c0] + a0 + gbias[c0];
  float t1 = h[(size_t)n*128+c1] + a1 + gbias[c1];
  float sm = t0+t1;
  #pragma unroll
  for (int mk=1; mk<64; mk<<=1) sm += __shfl_xor(sm,mk);
  float mean = sm * (1.f/128.f);
  float d0=t0-mean, d1=t1-mean;
  float vs = d0*d0 + d1*d1;
  #pragma unroll
  for (int mk=1; mk<64; mk<<=1) vs += __shfl_xor(vs,mk);
  float inv = rsqrtf(vs*(1.f/128.f) + 1e-5f);
  h[(size_t)n*128+c0] = d0*inv*lng[c0] + lnb[c0];
  h[(size_t)n*128+c1] = d1*inv*lng[c1] + lnb[c1];
}

// ---------------- node logits ----------------
__global__ __launch_bounds__(256) void k_nl(const float* __restrict__ h,
    const u16* __restrict__ aW1Th, const u16* __restrict__ aW1Tl,
    const float* __restrict__ ab1, const float* __restrict__ aW2, const float* __restrict__ ab2,
    float* __restrict__ nl){
  __shared__ u16 hth[64*136], htl[64*136];
  int rb = blockIdx.x*64, t=threadIdx.x, lane=t&63;
  { int r = t>>2, q = t&3;
    const f32x4* s = (const f32x4*)(h + (size_t)(rb+r)*128 + q*32);
    #pragma unroll
    for (int i=0;i<8;i++){
      f32x4 v = s[i];
      u16x4 oh, ol;
      #pragma unroll
      for (int j=0;j<4;j++){ u16 hh,ll; splitf(v[j],hh,ll); oh[j]=hh; ol[j]=ll; }
      *(u16x4*)&hth[r*136 + q*32 + 4*i] = oh;
      *(u16x4*)&htl[r*136 + q*32 + 4*i] = ol;
    }
  }
  __syncthreads();
  int w=t>>6, l15=t&15, g=(t&63)>>4;
  f32x4 acc[8];
  #pragma unroll
  for (int j=0;j<8;j++) acc[j] = (f32x4){0.f,0.f,0.f,0.f};
  #pragma unroll
  for (int kk=0; kk<4; kk++){
    bf16x8 ah = *(const bf16x8*)&hth[(16*w + l15)*136 + 32*kk + 8*g];
    bf16x8 al = *(const bf16x8*)&htl[(16*w + l15)*136 + 32*kk + 8*g];
    #pragma unroll
    for (int tc=0; tc<8; tc++){
      bf16x8 bh = WF(aW1Th, kk*8+tc, lane);
      bf16x8 bl_ = WF(aW1Tl, kk*8+tc, lane);
      acc[tc] = MFMA(ah,bh,acc[tc]);
      acc[tc] = MFMA(ah,bl_,acc[tc]);
      acc[tc] = MFMA(al,bh,acc[tc]);
    }
  }
  float s[4] = {0.f,0.f,0.f,0.f};
  #pragma unroll
  for (int tc=0; tc<8; tc++){
    int col = 16*tc + l15;
    float a2 = aW2[col];
    float b1 = ab1[col];
    #pragma unroll
    for (int j=0;j<4;j++){
      float v = acc[tc][j] + b1;
      v = v>0.f? v : 0.f;
      s[j] += v*a2;
    }
  }
  #pragma unroll
  for (int mk=1; mk<16; mk<<=1){
    #pragma unroll
    for (int j=0;j<4;j++) s[j] += __shfl_xor(s[j], mk);
  }
  if (l15==0){
    float b2 = ab2[0];
    #pragma unroll
    for (int j=0;j<4;j++) nl[rb + 16*w + 4*g + j] = s[j] + b2;
  }
}

// ---------------- per-graph mean/max/min, 2-stage ----------------
__global__ __launch_bounds__(256) void k_gf1(const float* __restrict__ h, float* __restrict__ gfp){
  __shared__ float red[3][2][128];
  int b = blockIdx.x;             // 128 blocks: (graph g, slice sl of 256 rows)
  int g = b>>3, sl = b&7;
  int t = threadIdx.x; int c = t&127, hh = t>>7;
  const float* p = h + (size_t)g*2048*128 + (size_t)(sl*256 + hh*128)*128 + c;
  float s=0.f, mx=-1e30f, mn=1e30f;
  for (int i=0;i<128;i++){ float v = p[(size_t)i*128]; s+=v; mx=fmaxf(mx,v); mn=fminf(mn,v); }
  red[0][hh][c]=s; red[1][hh][c]=mx; red[2][hh][c]=mn;
  __syncthreads();
  if (hh==0){
    gfp[b*384 + c]       = s + red[0][1][c];
    gfp[b*384 + 128 + c] = fmaxf(mx, red[1][1][c]);
    gfp[b*384 + 256 + c] = fminf(mn, red[2][1][c]);
  }
}
__global__ void k_gf2(const float* __restrict__ gfp, float* __restrict__ gf){
  int g = blockIdx.x, c = threadIdx.x;  // 16 x 128
  float S=0.f, MX=-1e30f, MN=1e30f;
  for (int k=0;k<8;k++){
    const float* q = gfp + (g*8+k)*384;
    S += q[c]; MX=fmaxf(MX,q[128+c]); MN=fminf(MN,q[256+c]);
  }
  gf[g*384+c]=S*(1.f/2048.f); gf[g*384+128+c]=MX; gf[g*384+256+c]=MN;
}

// ---------------- per-graph argmax / log_softmax / entropy ----------------
__global__ __launch_bounds__(256) void k_action(const float* __restrict__ nl, float* __restrict__ out){
  __shared__ float vmax[256]; __shared__ int vidx[256];
  __shared__ float r1[256], r2[256];
  int g = blockIdx.x, t = threadIdx.x;
  const float* p = nl + g*2048;
  float mx = -1e30f; int mi = 0;
  for (int i=t;i<2048;i+=256){ float v=p[i]; if (v>mx){mx=v;mi=i;} }
  vmax[t]=mx; vidx[t]=mi; __syncthreads();
  for (int s=128;s>0;s>>=1){
    if (t<s){
      float vo=vmax[t+s]; int io=vidx[t+s];
      if (vo > vmax[t] || (vo==vmax[t] && io<vidx[t])){ vmax[t]=vo; vidx[t]=io; }
    }
    __syncthreads();
  }
  float M = vmax[0]; int A = vidx[0];
  float s1=0.f, sl=0.f;
  for (int i=t;i<2048;i+=256){ float d=p[i]-M; float e=__expf(d); s1+=e; sl+=d*e; }
  r1[t]=s1; r2[t]=sl; __syncthreads();
  for (int s=128;s>0;s>>=1){ if (t<s){ r1[t]+=r1[t+s]; r2[t]+=r2[t+s]; } __syncthreads(); }
  if (t==0){
    float S=r1[0], SL=r2[0];
    out[g]      = (float)A;
    out[16+g]   = -logf(S);
    out[32+g]   = logf(S) - SL/S;
  }
}

// ---------------- value head ----------------
__global__ void k_value(const float* __restrict__ gf,
    const float* __restrict__ gnW, const float* __restrict__ gnb,
    const float* __restrict__ gng, const float* __restrict__ gnbeta,
    const float* __restrict__ cW1, const float* __restrict__ cb1,
    const float* __restrict__ cW2, const float* __restrict__ cb2,
    float* __restrict__ out){
  __shared__ float gfL[384]; __shared__ float u[128]; __shared__ float red[128];
  int g = blockIdx.x, t = threadIdx.x;   // 128 threads
  for (int i=t;i<384;i+=128) gfL[i] = gf[g*384+i];
  __syncthreads();
  float acc = gnb[t];
  for (int k=0;k<384;k++) acc += gfL[k]*gnW[k*128+t];
  acc = fmaxf(acc, 0.f);
  red[t]=acc; __syncthreads();
  for (int s=64;s>0;s>>=1){ if(t<s) red[t]+=red[t+s]; __syncthreads(); }
  float mean = red[0]*(1.f/128.f); __syncthreads();
  float dd = acc-mean; red[t]=dd*dd; __syncthreads();
  for (int s=64;s>0;s>>=1){ if(t<s) red[t]+=red[t+s]; __syncthreads(); }
  float var = red[0]*(1.f/128.f); __syncthreads();
  u[t] = dd*rsqrtf(var + 1e-5f)*gng[t] + gnbeta[t];
  __syncthreads();
  float a2 = cb1[t];
  for (int k=0;k<128;k++) a2 += u[k]*cW1[k*128+t];
  a2 = fmaxf(a2, 0.f);
  red[t] = a2*cW2[t]; __syncthreads();
  for (int s=64;s>0;s>>=1){ if(t<s) red[t]+=red[t+s]; __syncthreads(); }
  if (t==0) out[48+g] = red[0] + cb2[0];
}

// ---------------- launch ----------------
extern "C" void kernel_launch(void* const* d_in, const int* in_sizes, int n_in,
                              void* d_out, int out_size, void* d_ws, size_t ws_size,
                              hipStream_t stream) {
  (void)in_sizes; (void)n_in; (void)out_size; (void)ws_size;
  const float* x    = (const float*)d_in[0];
  const float* ea   = (const float*)d_in[1];
  const int*   ei   = (const int*)d_in[2];
  const float* Wn   = (const float*)d_in[4];
  const float* bn   = (const float*)d_in[5];
  const float* Wep  = (const float*)d_in[6];
  const float* bep  = (const float*)d_in[7];
  const float* gWl  = (const float*)d_in[8];
  const float* gbl  = (const float*)d_in[9];
  const float* gWr  = (const float*)d_in[10];
  const float* gbr  = (const float*)d_in[11];
  const float* gWe  = (const float*)d_in[12];
  const float* gatt = (const float*)d_in[13];
  const float* gbias= (const float*)d_in[14];
  const float* lng  = (const float*)d_in[15];
  const float* lnb  = (const float*)d_in[16];
  const float* gnW  = (const float*)d_in[17];
  const float* gnb  = (const float*)d_in[18];
  const float* gng  = (const float*)d_in[19];
  const float* gnbt = (const float*)d_in[20];
  const float* aW1  = (const float*)d_in[25];
  const float* ab1  = (const float*)d_in[26];
  const float* aW2  = (const float*)d_in[27];
  const float* ab2  = (const float*)d_in[28];
  const float* cW1  = (const float*)d_in[29];
  const float* cb1  = (const float*)d_in[30];
  const float* cW2  = (const float*)d_in[31];
  const float* cb2  = (const float*)d_in[32];
  float* out = (float*)d_out;

  char* W = (char*)d_ws;
  float* h      = (float*)(W + 0);
  float* xl     = (float*)(W + 16777216);
  float* xr     = (float*)(W + 33554432);
  float* logit  = (float*)(W + 50331648);
  int*   srcs   = (int*)  (W + 54525952);
  int*   eids   = (int*)  (W + 56623104);
  int*   cnt    = (int*)  (W + 58720256);
  int*   off    = (int*)  (W + 58851328);
  int*   cur    = (int*)  (W + 58982656);
  float* nl     = (float*)(W + 59113728);
  float* gf     = (float*)(W + 59244800);
  u16*   WnTh   = (u16*)  (W + 59269376);
  u16*   WnTl   = WnTh  + 8192;
  u16*   WepTh  = WnTl  + 8192;
  u16*   WepTl  = WepTh + 4096;
  u16*   WlTh   = WepTl + 4096;
  u16*   WlTl   = WlTh  + 49152;
  u16*   WrTh   = WlTl  + 49152;
  u16*   WrTl   = WrTh  + 49152;
  u16*   WeTh   = WrTl  + 49152;
  u16*   WeTl   = WeTh  + 49152;
  u16*   aW1Th  = WeTl  + 49152;
  u16*   aW1Tl  = aW1Th + 16384;
  float* gfp    = (float*)(W + 59973888);   // 128*384*4 = 196.6 KB
  float* easf   = (float*)(W + 60817408);   // E*32 fp32 = 67.1 MB

  (void)hipMemsetAsync(cnt, 0, NN*sizeof(int), stream);
  k_hist<<<NE/256, 256, 0, stream>>>(ei + NE, cnt);
  k_scan<<<1, 1024, 0, stream>>>(cnt, off, cur);
  k_scatter<<<NE/256, 256, 0, stream>>>(ei, cur, srcs, eids);
  k_presort<<<NE/64, 256, 0, stream>>>(ea, eids, easf);

  TP tp;
  tp.s[0]=Wn;  tp.dh[0]=WnTh;  tp.dl[0]=WnTl;  tp.K[0]=64;
  tp.s[1]=Wep; tp.dh[1]=WepTh; tp.dl[1]=WepTl; tp.K[1]=32;
  for (int l=0;l<3;l++){
    tp.s[2+l]=gWl + l*16384; tp.dh[2+l]=WlTh + l*16384; tp.dl[2+l]=WlTl + l*16384; tp.K[2+l]=128;
    tp.s[5+l]=gWr + l*16384; tp.dh[5+l]=WrTh + l*16384; tp.dl[5+l]=WrTl + l*16384; tp.K[5+l]=128;
    tp.s[8+l]=gWe + l*16384; tp.dh[8+l]=WeTh + l*16384; tp.dl[8+l]=WeTl + l*16384; tp.K[8+l]=128;
  }
  tp.s[11]=aW1; tp.dh[11]=aW1Th; tp.dl[11]=aW1Tl; tp.K[11]=128;
  k_transpose<<<12, 256, 0, stream>>>(tp);

  k_h0<<<NN/128, 256, 0, stream>>>(x, WnTh, WnTl, bn, h);

  for (int l=0; l<3; l++){
    k_xlr<<<NN/64, 256, 0, stream>>>(h, WlTh + l*16384, WlTl + l*16384,
                                     WrTh + l*16384, WrTl + l*16384,
                                     gbl + l*128, gbr + l*128, xl, xr);
    k_edge<<<NE/64, 256, 0, stream>>>(easf, WepTh, WepTl, bep,
                                      WeTh + l*16384, WeTl + l*16384, gatt + l*128,
                                      xl, xr, srcs, logit);
    k_aggr<<<NN/4, 256, 0, stream>>>(xl, logit, srcs, off,
                                     gbias + l*128, lng + l*128, lnb + l*128, h);
  }

  k_nl<<<NN/64, 256, 0, stream>>>(h, aW1Th, aW1Tl, ab1, aW2, ab2, nl);
  k_gf1<<<128, 256, 0, stream>>>(h, gfp);
  k_gf2<<<NG, 128, 0, stream>>>(gfp, gf);
  k_action<<<NG, 256, 0, stream>>>(nl, out);
  k_value<<<NG, 128, 0, stream>>>(gf, gnW, gnb, gng, gnbt,
                                  cW1, cb1, cW2, cb2, out);
}